// Round 3
// baseline (218.030 us; speedup 1.0000x reference)
//
#include <hip/hip_runtime.h>
#include <stdint.h>

#define ROWS   4096
#define NCOL   8192
#define TARGET 7680
#define NW     (NCOL - TARGET + 1)   // 513 windows
#define NT     512                   // threads per block (8 waves)
#define VPT    (NCOL / NT)           // 16 values per thread (in VGPRs)
#define NB     2048                  // histogram bins
#define BPT    (NB / NT)             // 4 bins per thread in scan
#define NWAVE  (NT / 64)             // 8 waves
#define SCAP   2048                  // sorted-buffer capacity (typ. tot ~1030)
#define MAXS   (SCAP / NT)           // max slots per thread in fixup (4)

struct Smem {
    uint32_t hist[NB];       // transposed: logical bin b at ((b&3)<<9)|(b>>2)
    float    sorted[SCAP];   // scattered candidates (unordered within bin)
    float    sorted2[SCAP];  // fixup output: exact sorted tails
    uint32_t wsum[NWAVE];
    uint32_t res[4];         // [0]=B_lo [1]=cntB(incl at B_lo) [2]=B_hi [3]=topBase(excl at B_hi)
    float    fmin[NWAVE], fmax[NWAVE];
    float    rv[NWAVE];
    int      ri[NWAVE];
};

__device__ __forceinline__ int bin1f(float v, float mn, float s) {
    int b = (int)((v - mn) * s);
    return b < 0 ? 0 : (b > NB - 1 ? NB - 1 : b);
}
// transposed physical index: scan phase reads hist[(j<<9)|tid] lane-consecutively
// (conflict-free); atomics hash on bin bits 2..6 (random for random values).
__device__ __forceinline__ int HIX(int b) { return ((b & 3) << 9) | (b >> 2); }

__global__ __launch_bounds__(NT, 8)
void recall_window_kernel(const float* __restrict__ x, float* __restrict__ out) {
    __shared__ Smem sm;
    const int tid = threadIdx.x;
    const int row = blockIdx.x;
    const int lane = tid & 63, wid = tid >> 6;

    // ---- Load row into registers (coalesced 16B) ----
    float v[VPT];
    const float4* xv = (const float4*)(x + (size_t)row * NCOL);
    #pragma unroll
    for (int j = 0; j < VPT / 4; j++) {
        float4 t = xv[tid + j * NT];
        v[4 * j + 0] = t.x; v[4 * j + 1] = t.y;
        v[4 * j + 2] = t.z; v[4 * j + 3] = t.w;
    }

    // ---- Block min/max (+ zero hist in same phase) ----
    float mn = v[0], mx = v[0];
    #pragma unroll
    for (int j = 1; j < VPT; j++) { mn = fminf(mn, v[j]); mx = fmaxf(mx, v[j]); }
    #pragma unroll
    for (int off = 32; off > 0; off >>= 1) {
        mn = fminf(mn, __shfl_down(mn, off, 64));
        mx = fmaxf(mx, __shfl_down(mx, off, 64));
    }
    if (lane == 0) { sm.fmin[wid] = mn; sm.fmax[wid] = mx; }
    #pragma unroll
    for (int j = 0; j < BPT; j++) sm.hist[tid + j * NT] = 0;
    __syncthreads();                                             // S1
    #pragma unroll
    for (int w = 0; w < NWAVE; w++) {
        mn = fminf(mn, sm.fmin[w]);
        mx = fmaxf(mx, sm.fmax[w]);
    }

    if (!(mx > mn)) {   // all values equal (uniform branch)
        if (tid == 0) { out[row] = mn; out[ROWS + row] = mn; }
        return;
    }
    const float scale1 = (float)NB / (mx - mn);

    // ---- L1: value-linear histogram (transposed-layout atomics) ----
    #pragma unroll
    for (int j = 0; j < VPT; j++)
        atomicAdd(&sm.hist[HIX(bin1f(v[j], mn, scale1))], 1u);
    __syncthreads();                                             // S2

    // ---- Single scan: locate rank bins + write scatter bases ----
    uint32_t h[BPT], s0 = 0;
    #pragma unroll
    for (int j = 0; j < BPT; j++) { h[j] = sm.hist[(j << 9) | tid]; s0 += h[j]; }
    uint32_t sc = s0;
    #pragma unroll
    for (int off = 1; off < 64; off <<= 1) {
        uint32_t n = __shfl_up(sc, off, 64);
        if (lane >= off) sc += n;
    }
    if (lane == 63) sm.wsum[wid] = sc;
    __syncthreads();                                             // S3
    uint32_t woff = 0;
    #pragma unroll
    for (int w = 0; w < NWAVE; w++) if (w < wid) woff += sm.wsum[w];
    const uint32_t incl = sc + woff, excl = incl - s0;
    const uint32_t ka = NW - 1, kb = TARGET - 1;
    if (ka >= excl && ka < incl) {           // bin of rank 512 (bottom tail end)
        uint32_t c = excl; bool done = false;
        #pragma unroll
        for (int j = 0; j < BPT; j++) {
            if (!done) {
                if (ka < c + h[j]) {
                    sm.res[0] = (uint32_t)(tid * BPT + j);
                    sm.res[1] = c + h[j];    // cntB = inclusive prefix at B_lo
                    done = true;
                } else c += h[j];
            }
        }
    }
    if (kb >= excl && kb < incl) {           // bin of rank 7679 (top tail start)
        uint32_t c = excl; bool done = false;
        #pragma unroll
        for (int j = 0; j < BPT; j++) {
            if (!done) {
                if (kb < c + h[j]) {
                    sm.res[2] = (uint32_t)(tid * BPT + j);
                    sm.res[3] = c;           // topBase = exclusive prefix at B_hi
                    done = true;
                } else c += h[j];
            }
        }
    }
    {   // overwrite counts with exclusive-prefix bases (independent of res)
        uint32_t run = excl;
        #pragma unroll
        for (int j = 0; j < BPT; j++) { sm.hist[(j << 9) | tid] = run; run += h[j]; }
    }
    __syncthreads();                                             // S4
    const int      B_lo    = (int)sm.res[0];
    const uint32_t cntB    = sm.res[1];
    const int      B_hi    = (int)sm.res[2];
    const uint32_t topBase = sm.res[3];
    const uint32_t shiftT  = cntB - topBase;     // mod-2^32; top slot = excl + shiftT
    uint32_t tot = cntB + (uint32_t)NCOL - topBase;
    if (tot > SCAP) tot = SCAP;

    // ---- Scatter candidates directly to global-rank slots ----
    // bottom (b<=B_lo): slot = excl_prefix + intra = global rank
    // top    (b>=B_hi): slot = excl_prefix + intra + shiftT
    #pragma unroll
    for (int j = 0; j < VPT; j++) {
        float val = v[j];
        int b = bin1f(val, mn, scale1);
        if (b <= B_lo || b >= B_hi) {
            uint32_t pos = atomicAdd(&sm.hist[HIX(b)], 1u);
            if (b >= B_hi) pos += shiftT;
            if (pos < SCAP) sm.sorted[pos] = val;
        }
    }
    __syncthreads();                                             // S5
    // now hist[b] = exclusive prefix + count = inclusive end (unshifted for top)

    // ---- Fix-up: rank within L1 bins, write to sorted2 (no WB hazard) ----
    #pragma unroll
    for (int it = 0; it < MAXS; it++) {
        int s = tid + it * NT;
        if (s < (int)tot) {
            float vv = sm.sorted[s];
            int b = bin1f(vv, mn, scale1);
            uint32_t en = sm.hist[HIX(b)];
            uint32_t st;
            if (s < (int)cntB) {
                st = (b == 0) ? 0u : sm.hist[HIX(b - 1)];
            } else {
                st = (b == B_hi) ? topBase : sm.hist[HIX(b - 1)];
                st += shiftT; en += shiftT;
            }
            if (en > tot) en = tot;
            uint32_t r = 0;
            if (en - st > 1) {
                for (uint32_t q = st; q < en; q++) {
                    float u = sm.sorted[q];
                    r += (u < vv) || (u == vv && (int)q < s);
                }
            }
            uint32_t d = st + r;
            if (d < SCAP) sm.sorted2[d] = vv;
        }
    }
    __syncthreads();                                             // S6

    // sorted2[0..cntB) = global ranks 0..cntB-1 ascending;
    // sorted2[cntB..tot) = global ranks topBase..8191 ascending.
    // window i: left = sorted2[i]; right = sorted2[tot - NW + i]

    // ---- lengths + first-occurrence argmin ----
    const int topstart = (int)tot - NW;
    float lbest = __int_as_float(0x7F800000);   // +inf
    int   lidx  = 0x7FFFFFFF;
    for (int i = tid; i < NW; i += NT) {
        float len = sm.sorted2[topstart + i] - sm.sorted2[i];
        if (len < lbest) { lbest = len; lidx = i; }
    }
    #pragma unroll
    for (int off = 32; off > 0; off >>= 1) {
        float v2 = __shfl_down(lbest, off, 64);
        int   i2 = __shfl_down(lidx,  off, 64);
        if (v2 < lbest || (v2 == lbest && i2 < lidx)) { lbest = v2; lidx = i2; }
    }
    if (lane == 0) { sm.rv[wid] = lbest; sm.ri[wid] = lidx; }
    __syncthreads();                                             // S7
    if (tid == 0) {
        float bv = sm.rv[0]; int bi = sm.ri[0];
        #pragma unroll
        for (int w = 1; w < NWAVE; w++) {
            float v2 = sm.rv[w]; int i2 = sm.ri[w];
            if (v2 < bv || (v2 == bv && i2 < bi)) { bv = v2; bi = i2; }
        }
        out[row]        = sm.sorted2[bi];             // left  = s[idx]
        out[ROWS + row] = sm.sorted2[topstart + bi];  // right = s[idx+target-1]
    }
}

extern "C" void kernel_launch(void* const* d_in, const int* in_sizes, int n_in,
                              void* d_out, int out_size, void* d_ws, size_t ws_size,
                              hipStream_t stream) {
    const float* x = (const float*)d_in[0];
    float* out = (float*)d_out;
    recall_window_kernel<<<ROWS, NT, 0, stream>>>(x, out);
}

// Round 4
// 192.513 us; speedup vs baseline: 1.1325x; 1.1325x over previous
//
#include <hip/hip_runtime.h>
#include <stdint.h>

#define ROWS   4096
#define NCOL   8192
#define TARGET 7680
#define NW     (NCOL - TARGET + 1)   // 513 windows
#define NT     512                   // threads per block (8 waves)
#define VPT    (NCOL / NT)           // 16 values per thread (in VGPRs)
#define NB     2048                  // histogram bins
#define BPT    (NB / NT)             // 4 bins per thread in scan
#define NWAVE  (NT / 64)             // 8 waves
#define SCAP   2048                  // sorted-buffer capacity (typ. tot ~1030)
#define MAXS   (SCAP / NT)           // max slots per thread in fixup (4)

struct Smem {
    uint32_t hist[NB];       // transposed: logical bin b at ((b&3)<<9)|(b>>2)
    float    sorted[SCAP];   // scattered candidates (unordered within bin)
    float    sorted2[SCAP];  // fixup output: exact sorted tails
    uint32_t wsum[NWAVE];
    uint32_t res[4];         // [0]=B_lo [1]=cntB(incl at B_lo) [2]=B_hi [3]=topBase(excl at B_hi)
    float    fmin[NWAVE], fmax[NWAVE];
    float    rv[NWAVE];
    int      ri[NWAVE];
};

__device__ __forceinline__ int bin1f(float v, float mn, float s) {
    int b = (int)((v - mn) * s);
    return b < 0 ? 0 : (b > NB - 1 ? NB - 1 : b);
}
// transposed physical index: scan phase reads hist[(j<<9)|tid] lane-consecutively
// (conflict-free); atomics hash on bin bits 2..6 (random for random values).
__device__ __forceinline__ int HIX(int b) { return ((b & 3) << 9) | (b >> 2); }

// launch_bounds(512,4): 128-VGPR budget. (512,8) forced a 64-VGPR budget that
// spilled v[] to scratch (round-3: WRITE_SIZE 3.8->106 MB, dur 86us). Natural
// allocation here is ~48-64 VGPR -> still 8 waves/EU, no spill.
__global__ __launch_bounds__(NT, 4)
void recall_window_kernel(const float* __restrict__ x, float* __restrict__ out) {
    __shared__ Smem sm;
    const int tid = threadIdx.x;
    const int row = blockIdx.x;
    const int lane = tid & 63, wid = tid >> 6;

    // ---- Load row into registers (coalesced 16B), min/max fused so the
    //      float4 staging temps die immediately (lower peak VGPR) ----
    float v[VPT];
    float mn = __int_as_float(0x7F800000), mx = -mn;
    const float4* xv = (const float4*)(x + (size_t)row * NCOL);
    #pragma unroll
    for (int j = 0; j < VPT / 4; j++) {
        float4 t = xv[tid + j * NT];
        v[4 * j + 0] = t.x; v[4 * j + 1] = t.y;
        v[4 * j + 2] = t.z; v[4 * j + 3] = t.w;
        mn = fminf(mn, fminf(fminf(t.x, t.y), fminf(t.z, t.w)));
        mx = fmaxf(mx, fmaxf(fmaxf(t.x, t.y), fmaxf(t.z, t.w)));
    }

    // ---- Block min/max (+ zero hist in same phase) ----
    #pragma unroll
    for (int off = 32; off > 0; off >>= 1) {
        mn = fminf(mn, __shfl_down(mn, off, 64));
        mx = fmaxf(mx, __shfl_down(mx, off, 64));
    }
    if (lane == 0) { sm.fmin[wid] = mn; sm.fmax[wid] = mx; }
    #pragma unroll
    for (int j = 0; j < BPT; j++) sm.hist[tid + j * NT] = 0;
    __syncthreads();                                             // S1
    #pragma unroll
    for (int w = 0; w < NWAVE; w++) {
        mn = fminf(mn, sm.fmin[w]);
        mx = fmaxf(mx, sm.fmax[w]);
    }

    if (!(mx > mn)) {   // all values equal (uniform branch)
        if (tid == 0) { out[row] = mn; out[ROWS + row] = mn; }
        return;
    }
    const float scale1 = (float)NB / (mx - mn);

    // ---- L1: value-linear histogram (transposed-layout atomics) ----
    #pragma unroll
    for (int j = 0; j < VPT; j++)
        atomicAdd(&sm.hist[HIX(bin1f(v[j], mn, scale1))], 1u);
    __syncthreads();                                             // S2

    // ---- Single scan: locate rank bins + write scatter bases ----
    uint32_t h[BPT], s0 = 0;
    #pragma unroll
    for (int j = 0; j < BPT; j++) { h[j] = sm.hist[(j << 9) | tid]; s0 += h[j]; }
    uint32_t sc = s0;
    #pragma unroll
    for (int off = 1; off < 64; off <<= 1) {
        uint32_t n = __shfl_up(sc, off, 64);
        if (lane >= off) sc += n;
    }
    if (lane == 63) sm.wsum[wid] = sc;
    __syncthreads();                                             // S3
    uint32_t woff = 0;
    #pragma unroll
    for (int w = 0; w < NWAVE; w++) if (w < wid) woff += sm.wsum[w];
    const uint32_t incl = sc + woff, excl = incl - s0;
    const uint32_t ka = NW - 1, kb = TARGET - 1;
    if (ka >= excl && ka < incl) {           // bin of rank 512 (bottom tail end)
        uint32_t c = excl; bool done = false;
        #pragma unroll
        for (int j = 0; j < BPT; j++) {
            if (!done) {
                if (ka < c + h[j]) {
                    sm.res[0] = (uint32_t)(tid * BPT + j);
                    sm.res[1] = c + h[j];    // cntB = inclusive prefix at B_lo
                    done = true;
                } else c += h[j];
            }
        }
    }
    if (kb >= excl && kb < incl) {           // bin of rank 7679 (top tail start)
        uint32_t c = excl; bool done = false;
        #pragma unroll
        for (int j = 0; j < BPT; j++) {
            if (!done) {
                if (kb < c + h[j]) {
                    sm.res[2] = (uint32_t)(tid * BPT + j);
                    sm.res[3] = c;           // topBase = exclusive prefix at B_hi
                    done = true;
                } else c += h[j];
            }
        }
    }
    {   // overwrite counts with exclusive-prefix bases (independent of res)
        uint32_t run = excl;
        #pragma unroll
        for (int j = 0; j < BPT; j++) { sm.hist[(j << 9) | tid] = run; run += h[j]; }
    }
    __syncthreads();                                             // S4
    const int      B_lo    = (int)sm.res[0];
    const uint32_t cntB    = sm.res[1];
    const int      B_hi    = (int)sm.res[2];
    const uint32_t topBase = sm.res[3];
    const uint32_t shiftT  = cntB - topBase;     // mod-2^32; top slot = excl + shiftT
    uint32_t tot = cntB + (uint32_t)NCOL - topBase;
    if (tot > SCAP) tot = SCAP;

    // ---- Scatter candidates directly to global-rank slots ----
    // bottom (b<=B_lo): slot = excl_prefix + intra = global rank
    // top    (b>=B_hi): slot = excl_prefix + intra + shiftT
    #pragma unroll
    for (int j = 0; j < VPT; j++) {
        float val = v[j];
        int b = bin1f(val, mn, scale1);
        if (b <= B_lo || b >= B_hi) {
            uint32_t pos = atomicAdd(&sm.hist[HIX(b)], 1u);
            if (b >= B_hi) pos += shiftT;
            if (pos < SCAP) sm.sorted[pos] = val;
        }
    }
    __syncthreads();                                             // S5
    // now hist[b] = exclusive prefix + count = inclusive end (unshifted for top)

    // ---- Fix-up: rank within L1 bins, write to sorted2 (no WB hazard) ----
    #pragma unroll
    for (int it = 0; it < MAXS; it++) {
        int s = tid + it * NT;
        if (s < (int)tot) {
            float vv = sm.sorted[s];
            int b = bin1f(vv, mn, scale1);
            uint32_t en = sm.hist[HIX(b)];
            uint32_t st;
            if (s < (int)cntB) {
                st = (b == 0) ? 0u : sm.hist[HIX(b - 1)];
            } else {
                st = (b == B_hi) ? topBase : sm.hist[HIX(b - 1)];
                st += shiftT; en += shiftT;
            }
            if (en > tot) en = tot;
            uint32_t r = 0;
            if (en - st > 1) {
                for (uint32_t q = st; q < en; q++) {
                    float u = sm.sorted[q];
                    r += (u < vv) || (u == vv && (int)q < s);
                }
            }
            uint32_t d = st + r;
            if (d < SCAP) sm.sorted2[d] = vv;
        }
    }
    __syncthreads();                                             // S6

    // sorted2[0..cntB) = global ranks 0..cntB-1 ascending;
    // sorted2[cntB..tot) = global ranks topBase..8191 ascending.
    // window i: left = sorted2[i]; right = sorted2[tot - NW + i]

    // ---- lengths + first-occurrence argmin ----
    const int topstart = (int)tot - NW;
    float lbest = __int_as_float(0x7F800000);   // +inf
    int   lidx  = 0x7FFFFFFF;
    for (int i = tid; i < NW; i += NT) {
        float len = sm.sorted2[topstart + i] - sm.sorted2[i];
        if (len < lbest) { lbest = len; lidx = i; }
    }
    #pragma unroll
    for (int off = 32; off > 0; off >>= 1) {
        float v2 = __shfl_down(lbest, off, 64);
        int   i2 = __shfl_down(lidx,  off, 64);
        if (v2 < lbest || (v2 == lbest && i2 < lidx)) { lbest = v2; lidx = i2; }
    }
    if (lane == 0) { sm.rv[wid] = lbest; sm.ri[wid] = lidx; }
    __syncthreads();                                             // S7
    if (tid == 0) {
        float bv = sm.rv[0]; int bi = sm.ri[0];
        #pragma unroll
        for (int w = 1; w < NWAVE; w++) {
            float v2 = sm.rv[w]; int i2 = sm.ri[w];
            if (v2 < bv || (v2 == bv && i2 < bi)) { bv = v2; bi = i2; }
        }
        out[row]        = sm.sorted2[bi];             // left  = s[idx]
        out[ROWS + row] = sm.sorted2[topstart + bi];  // right = s[idx+target-1]
    }
}

extern "C" void kernel_launch(void* const* d_in, const int* in_sizes, int n_in,
                              void* d_out, int out_size, void* d_ws, size_t ws_size,
                              hipStream_t stream) {
    const float* x = (const float*)d_in[0];
    float* out = (float*)d_out;
    recall_window_kernel<<<ROWS, NT, 0, stream>>>(x, out);
}